// Round 7
// baseline (766.820 us; speedup 1.0000x reference)
//
#include <hip/hip_runtime.h>
#include <hip/hip_bf16.h>

typedef __attribute__((ext_vector_type(8))) short bf16x8;
typedef __attribute__((ext_vector_type(4))) float f32x4;

static constexpr int NB   = 8;
static constexpr int NN   = 1024;
static constexpr int NE   = 32768;
static constexpr int FIN  = 128;
static constexpr int FH   = 256;
static constexpr int FOUT = 128;
static constexpr int MR   = NB * NN;

__device__ __forceinline__ short f2bf(float f) {
  union { __hip_bfloat16 h; short s; } u;
  u.h = __float2bfloat16(f);
  return u.s;
}

typedef const __attribute__((address_space(1))) void gas_void;
typedef __attribute__((address_space(3))) void las_void;
__device__ __forceinline__ void glds16(short* lds, const short* g) {
  __builtin_amdgcn_global_load_lds((gas_void*)g, (las_void*)lds, 16, 0, 0);
}
__device__ __forceinline__ void BAR() {
  asm volatile("" ::: "memory");
  __builtin_amdgcn_s_barrier();
  asm volatile("" ::: "memory");
}

// ---- graph preprocessing -------------------------------------------------
__global__ void k_deg(const int* __restrict__ dst, int* __restrict__ deg) {
  int e = blockIdx.x * blockDim.x + threadIdx.x;
  if (e < NE) atomicAdd(&deg[dst[e]], 1);
}
__global__ void k_dis(const int* __restrict__ deg, float* __restrict__ dis) {
  int n = blockIdx.x * blockDim.x + threadIdx.x;
  if (n < NN) dis[n] = rsqrtf((float)(deg[n] + 1));
}
__global__ void k_adj(const int* __restrict__ src, const int* __restrict__ dst,
                      const float* __restrict__ dis, float* __restrict__ Adj) {
  int t = blockIdx.x * blockDim.x + threadIdx.x;
  if (t < NE) {
    int s = src[t], d = dst[t];
    atomicAdd(&Adj[d * NN + s], dis[s] * dis[d]);
  } else if (t < NE + NN) {
    int n = t - NE;
    atomicAdd(&Adj[n * NN + n], dis[n] * dis[n]);
  }
}

// ---- layout / cast kernels ----------------------------------------------
__global__ __launch_bounds__(256) void k_tr(const float* __restrict__ S,
                                            short* __restrict__ D, int R, int C) {
  int idx = blockIdx.x * 256 + threadIdx.x;
  int r = idx / C, c = idx % C;
  D[(size_t)c * R + r] = f2bf(S[idx]);
}
__global__ __launch_bounds__(256) void k_cast(const float4* __restrict__ S,
                                              short* __restrict__ D) {
  size_t q = (size_t)blockIdx.x * 256 + threadIdx.x;
  float4 a = S[q];
  short4 p;
  p.x = f2bf(a.x); p.y = f2bf(a.y); p.z = f2bf(a.z); p.w = f2bf(a.w);
  *(short4*)&D[q * 4] = p;
}
__global__ __launch_bounds__(256) void k_prep_min(const float* __restrict__ S,
                                                  short* __restrict__ Bf,
                                                  short* __restrict__ Tn) {
  __shared__ short tile[64][72];
  int tid = threadIdx.x;
  int e0 = blockIdx.x * 64, n0 = blockIdx.y * 64;
  #pragma unroll
  for (int i = 0; i < 16; ++i) {
    int r = i * 4 + (tid >> 6);
    int c = tid & 63;
    short v = f2bf(S[(size_t)(e0 + r) * 1024 + n0 + c]);
    tile[c][r] = v;
    Bf[(size_t)(e0 + r) * 1024 + n0 + c] = v;
  }
  __syncthreads();
  int n = tid >> 2, ec = (tid & 3) * 16;
  #pragma unroll
  for (int q = 0; q < 4; ++q) {
    short4 v;
    v.x = tile[n][ec + q * 4 + 0];
    v.y = tile[n][ec + q * 4 + 1];
    v.z = tile[n][ec + q * 4 + 2];
    v.w = tile[n][ec + q * 4 + 3];
    *(short4*)&Tn[(size_t)(n0 + n) * 32768 + e0 + ec + q * 4] = v;
  }
}
// H2b[(b*1024+node)][f] = H2all[node][b*256+f]
__global__ __launch_bounds__(256) void k_repack(const float* __restrict__ H2all,
                                                short* __restrict__ H2b) {
  int q = blockIdx.x * 256 + threadIdx.x;      // quad over [8192][64]
  int row = q >> 6, f4 = (q & 63) << 2;
  int b = row >> 10, node = row & 1023;
  float4 v = *(const float4*)&H2all[(size_t)node * 2048 + b * 256 + f4];
  short4 p;
  p.x = f2bf(v.x); p.y = f2bf(v.y); p.z = f2bf(v.z); p.w = f2bf(v.w);
  *(short4*)&H2b[(size_t)row * 256 + f4] = p;
}

// ---- proven 128x128 bf16 MFMA GEMM (small convs / projections) -----------
template <int EPI, int ASRC, int BSEL, bool BIAS, bool RELU>
__launch_bounds__(256)
__global__ void gemm_mfma(const short* __restrict__ Ab, const float* __restrict__ Af,
                          const short* __restrict__ BT, const float* __restrict__ bias,
                          void* __restrict__ Cv,
                          int lda, int ldb, int ldc, int K, int kSplit, int nz2,
                          int zcolB, size_t szA, size_t szB, size_t szC, size_t szC2,
                          float scale) {
  __shared__ __align__(16) short As[128 * 64];
  __shared__ __align__(16) short Bs[128 * 64];

  const int tid = threadIdx.x;
  const int lane = tid & 63, wid = tid >> 6;
  const int wr = wid >> 1, wc = wid & 1;
  const int fr = lane & 15, fq = lane >> 4;
  const int m0 = blockIdx.y * 128, n0 = blockIdx.x * 128;

  int zA = 0, zB = 0, k0 = 0, k1 = K;
  if constexpr (EPI == 1) {
    k0 = blockIdx.z * kSplit; k1 = k0 + kSplit;
  } else {
    zA = (int)blockIdx.z % nz2; zB = (int)blockIdx.z / nz2;
  }
  if constexpr (ASRC == 0) Ab += (size_t)zA * szA;
  else                     Af += (size_t)zA * szA;
  BT += (size_t)zB * szB;
  const int colB = zB * zcolB;

  const int rq = lane >> 3;
  const int ks = (lane & 7) ^ rq;

  f32x4 acc[4][4] = {};

  for (int kt = k0; kt < k1; kt += 64) {
    if constexpr (ASRC == 2) {
      #pragma unroll
      for (int p = 0; p < 4; ++p) {
        int i = p * 256 + tid, row = i >> 3, g = i & 7;
        const float* ap = Af + (size_t)(m0 + row) * lda + kt + g * 8;
        bf16x8 v;
        #pragma unroll
        for (int e = 0; e < 8; ++e) v[e] = f2bf(ap[e]);
        *(bf16x8*)&As[row * 64 + ((g ^ (row & 7)) * 8)] = v;
      }
    } else {
      #pragma unroll
      for (int c = 0; c < 4; ++c) {
        int row = wid * 32 + c * 8 + rq;
        glds16(&As[(wid * 256 + c * 64) * 8],
               Ab + (size_t)(m0 + row) * lda + kt + ks * 8);
      }
    }
    {
      const short* Bsrc;
      int ldbe;
      if constexpr (BSEL == 1) { Bsrc = BT + colB; ldbe = 8192; }
      else                     { Bsrc = BT;        ldbe = ldb;  }
      #pragma unroll
      for (int c = 0; c < 4; ++c) {
        int row = wid * 32 + c * 8 + rq;
        glds16(&Bs[(wid * 256 + c * 64) * 8],
               Bsrc + (size_t)(n0 + row) * ldbe + kt + ks * 8);
      }
    }
    __syncthreads();
    bf16x8 afv[4][2], bfv[4][2];
    #pragma unroll
    for (int i = 0; i < 4; ++i) {
      int row = wr * 64 + i * 16 + fr;
      #pragma unroll
      for (int kh = 0; kh < 2; ++kh)
        afv[i][kh] = *(const bf16x8*)&As[row * 64 + (((kh * 4 + fq) ^ (fr & 7)) * 8)];
    }
    #pragma unroll
    for (int j = 0; j < 4; ++j) {
      int row = wc * 64 + j * 16 + fr;
      #pragma unroll
      for (int kh = 0; kh < 2; ++kh)
        bfv[j][kh] = *(const bf16x8*)&Bs[row * 64 + (((kh * 4 + fq) ^ (fr & 7)) * 8)];
    }
    #pragma unroll
    for (int i = 0; i < 4; ++i)
      #pragma unroll
      for (int j = 0; j < 4; ++j) {
        acc[i][j] = __builtin_amdgcn_mfma_f32_16x16x32_bf16(afv[i][0], bfv[j][0], acc[i][j], 0, 0, 0);
        acc[i][j] = __builtin_amdgcn_mfma_f32_16x16x32_bf16(afv[i][1], bfv[j][1], acc[i][j], 0, 0, 0);
      }
    __syncthreads();
  }

  const size_t cOff = (size_t)zB * szC + (size_t)zA * szC2;
  #pragma unroll
  for (int i = 0; i < 4; ++i) {
    int rowb = m0 + wr * 64 + i * 16 + fq * 4;
    #pragma unroll
    for (int j = 0; j < 4; ++j) {
      int col = n0 + wc * 64 + j * 16 + fr;
      float bv = 0.0f;
      if constexpr (BIAS) bv = bias[col];
      float v0 = acc[i][j][0] + bv, v1 = acc[i][j][1] + bv;
      float v2 = acc[i][j][2] + bv, v3 = acc[i][j][3] + bv;
      if constexpr (RELU) {
        v0 = fmaxf(v0, 0.0f); v1 = fmaxf(v1, 0.0f);
        v2 = fmaxf(v2, 0.0f); v3 = fmaxf(v3, 0.0f);
      }
      if constexpr (EPI == 0) {
        short* Ct = (short*)Cv + cOff;
        short4 pk;
        pk.x = f2bf(v0); pk.y = f2bf(v1); pk.z = f2bf(v2); pk.w = f2bf(v3);
        *(short4*)(Ct + (size_t)col * ldc + rowb) = pk;
      } else if constexpr (EPI == 1) {
        float* Cf = (float*)Cv;
        atomicAdd(&Cf[(size_t)(rowb + 0) * ldc + col], acc[i][j][0] * scale);
        atomicAdd(&Cf[(size_t)(rowb + 1) * ldc + col], acc[i][j][1] * scale);
        atomicAdd(&Cf[(size_t)(rowb + 2) * ldc + col], acc[i][j][2] * scale);
        atomicAdd(&Cf[(size_t)(rowb + 3) * ldc + col], acc[i][j][3] * scale);
      } else if constexpr (EPI == 2) {
        short* Cn = (short*)Cv + cOff;
        Cn[(size_t)(rowb + 0) * ldc + col] = f2bf(v0);
        Cn[(size_t)(rowb + 1) * ldc + col] = f2bf(v1);
        Cn[(size_t)(rowb + 2) * ldc + col] = f2bf(v2);
        Cn[(size_t)(rowb + 3) * ldc + col] = f2bf(v3);
      } else {
        float* Cf = (float*)Cv + cOff;
        Cf[(size_t)(rowb + 0) * ldc + col] = v0;
        Cf[(size_t)(rowb + 1) * ldc + col] = v1;
        Cf[(size_t)(rowb + 2) * ldc + col] = v2;
        Cf[(size_t)(rowb + 3) * ldc + col] = v3;
      }
    }
  }
}

// ---- 256x256 fat-phase counted-vmcnt GEMM: C = A[M,K] @ B[N,K]^T ---------
// 8 waves (2M x 4N), BK=64, double-buffered LDS (128 KiB), minimal LDS reads
// (24 b128/wave/K-tile), XCD-swizzled blocks, per-tile: stage(t+1) ->
// vmcnt(8) -> BAR -> reads+MFMA -> BAR  (loads never drain in steady state).
// ADUAL: A = (kt<1024 ? Ain : Aout)[row][kt&1023] (lda); else Ain[row][kt]
// EPI 0: bf16 transposed store C[col][ldc]+row, bias[col&255], relu
// EPI 1: fp32 atomicAdd C[row][ldc]+col * scale; z = split-K (kSplit per z)
template <int EPI, bool ADUAL>
__launch_bounds__(512, 2)
__global__ void eg256(const short* __restrict__ Ain, const short* __restrict__ Aout,
                      int lda, const short* __restrict__ Bm, int ldb,
                      const float* __restrict__ bias, void* __restrict__ Cv, int ldc,
                      int kSplit, float scale) {
  __shared__ __align__(16) short As[2][16384];
  __shared__ __align__(16) short Bs[2][16384];

  // XCD-aware bijective swizzle (requires gridDim.x*gridDim.y % 8 == 0)
  const int nbxy = gridDim.x * gridDim.y;
  const int obid = blockIdx.y * gridDim.x + blockIdx.x;
  const int cpx = nbxy >> 3;
  const int sb = (obid & 7) * cpx + (obid >> 3);
  const int bx = sb % gridDim.x, by = sb / gridDim.x;

  const int tid = threadIdx.x;
  const int lane = tid & 63, wid = tid >> 6;
  const int wm = wid >> 2, wn = wid & 3;
  const int fr = lane & 15, fq = lane >> 4;
  const int m0 = by * 256, n0 = bx * 256;

  const int k0 = (EPI == 1) ? (int)blockIdx.z * kSplit : 0;
  const int NT = kSplit / 64;

  const int rl = tid >> 3;
  const int ce = ((tid & 7) ^ (rl & 7)) << 3;
  const int ldst = wid << 9;

  f32x4 acc[8][4] = {};

  auto stage = [&](int buf, int t) {
    const int kt = k0 + t * 64;
    const short* a;
    if constexpr (ADUAL) a = (kt < 1024 ? Ain : Aout) + (kt & 1023);
    else                 a = Ain + kt;
    #pragma unroll
    for (int iss = 0; iss < 4; ++iss)
      glds16(&As[buf][iss * 4096 + ldst],
             a + (size_t)(m0 + iss * 64 + rl) * lda + ce);
    #pragma unroll
    for (int iss = 0; iss < 4; ++iss)
      glds16(&Bs[buf][iss * 4096 + ldst],
             Bm + (size_t)(n0 + iss * 64 + rl) * ldb + kt + ce);
  };

  stage(0, 0);
  for (int t = 0; t < NT; ++t) {
    const int buf = t & 1;
    if (t + 1 < NT) {
      stage(buf ^ 1, t + 1);
      asm volatile("s_waitcnt vmcnt(8)" ::: "memory");   // retire tile t only
    } else {
      asm volatile("s_waitcnt vmcnt(0)" ::: "memory");
    }
    BAR();   // tile t visible to all waves
    // B-stripe fragments (8 reads), then stream A rows (16 reads)
    bf16x8 bv[4][2];
    #pragma unroll
    for (int j = 0; j < 4; ++j) {
      int rb = wn * 64 + j * 16 + fr;
      #pragma unroll
      for (int s = 0; s < 2; ++s)
        bv[j][s] = *(const bf16x8*)&Bs[buf][rb * 64 + (((s * 4 + fq) ^ (rb & 7)) << 3)];
    }
    __builtin_amdgcn_s_setprio(1);
    #pragma unroll
    for (int i = 0; i < 8; ++i) {
      int r = wm * 128 + i * 16 + fr;
      bf16x8 a0 = *(const bf16x8*)&As[buf][r * 64 + (((0 + fq) ^ (r & 7)) << 3)];
      bf16x8 a1 = *(const bf16x8*)&As[buf][r * 64 + (((4 + fq) ^ (r & 7)) << 3)];
      #pragma unroll
      for (int j = 0; j < 4; ++j) {
        acc[i][j] = __builtin_amdgcn_mfma_f32_16x16x32_bf16(a0, bv[j][0], acc[i][j], 0, 0, 0);
        acc[i][j] = __builtin_amdgcn_mfma_f32_16x16x32_bf16(a1, bv[j][1], acc[i][j], 0, 0, 0);
      }
    }
    __builtin_amdgcn_s_setprio(0);
    BAR();   // all reads of buf retired before it is restaged
  }

  if constexpr (EPI == 0) {
    short* Ct = (short*)Cv;
    #pragma unroll
    for (int i = 0; i < 8; ++i) {
      int e = m0 + wm * 128 + i * 16 + fq * 4;
      #pragma unroll
      for (int j = 0; j < 4; ++j) {
        int col = n0 + wn * 64 + j * 16 + fr;
        float bb = bias[col & 255];
        short4 pk;
        pk.x = f2bf(fmaxf(acc[i][j][0] + bb, 0.0f));
        pk.y = f2bf(fmaxf(acc[i][j][1] + bb, 0.0f));
        pk.z = f2bf(fmaxf(acc[i][j][2] + bb, 0.0f));
        pk.w = f2bf(fmaxf(acc[i][j][3] + bb, 0.0f));
        *(short4*)&Ct[(size_t)col * ldc + e] = pk;
      }
    }
  } else {
    float* Cf = (float*)Cv;
    #pragma unroll
    for (int i = 0; i < 8; ++i) {
      int e = m0 + wm * 128 + i * 16 + fq * 4;
      #pragma unroll
      for (int j = 0; j < 4; ++j) {
        int col = n0 + wn * 64 + j * 16 + fr;
        #pragma unroll
        for (int r = 0; r < 4; ++r)
          atomicAdd(&Cf[(size_t)(e + r) * ldc + col], acc[i][j][r] * scale);
      }
    }
  }
}

// ---- launch --------------------------------------------------------------
extern "C" void kernel_launch(void* const* d_in, const int* in_sizes, int n_in,
                              void* d_out, int out_size, void* d_ws, size_t ws_size,
                              hipStream_t stream) {
  const float* x     = (const float*)d_in[0];
  const int*   ei    = (const int*)d_in[1];
  const float* m_in  = (const float*)d_in[2];
  const float* m_out = (const float*)d_in[3];
  const float* W1    = (const float*)d_in[4];
  const float* b1    = (const float*)d_in[5];
  const float* Wm    = (const float*)d_in[6];
  const float* bm    = (const float*)d_in[7];
  const float* W2    = (const float*)d_in[8];
  const float* b2    = (const float*)d_in[9];
  float* out = (float*)d_out;
  const int* src = ei;
  const int* dst = ei + NE;

  char* w = (char*)d_ws;
  size_t used = 0;
  auto alloc = [&](size_t bytes) {
    char* p = w; size_t r = (bytes + 255) & ~(size_t)255;
    w += r; used += r; return p;
  };
  float* dis    = (float*)alloc((size_t)NN * 4);
  int*   deg    = (int*)  alloc((size_t)NN * 4);
  short* Adjb   = (short*)alloc((size_t)NN * NN * 2);        // 2 MB (live to end)
  short* W1T    = (short*)alloc((size_t)FH * FIN * 2);
  short* WmT    = (short*)alloc((size_t)2 * FH * FH * 2);
  short* W2T    = (short*)alloc((size_t)FOUT * FH * 2);
  short* G2T    = (short*)alloc((size_t)2048 * 2048 * 2);    // 8 MB [(b,f)][(h,node)]
  float* H2all  = (float*)alloc((size_t)NN * 2048 * 4);      // 8 MB [node][(b,f)]
  short* m_in_bf  = (short*)alloc((size_t)NE * NN * 2);      // 64 MB
  short* m_out_bf = (short*)alloc((size_t)NE * NN * 2);      // 64 MB
  short* m_inT    = (short*)alloc((size_t)NN * NE * 2);      // 64 MB [1024][32768]

  // time-phased union region U: {Adj,XW1T,Hb} -> EbT -> {H2b,XW2T}
  int EC = 4096;
  for (int ec : {32768, 16384, 8192}) {
    size_t need = (size_t)ec * 2048 * 2;
    if (need < (12u << 20)) need = 12u << 20;
    if (used + need + (1u << 20) <= ws_size) { EC = ec; break; }
  }
  size_t ubytes = (size_t)EC * 2048 * 2;
  if (ubytes < (12u << 20)) ubytes = 12u << 20;
  char* U = alloc(ubytes);
  float* Adj  = (float*)U;                  // 4 MB   (early)
  short* XW1T = (short*)(U + (4u << 20));   // 4 MB   (early) [256][8192]
  short* Hb   = (short*)(U + (8u << 20));   // 4 MB   (early) [8192][256]
  short* EbT  = (short*)U;                  // EC*2048*2 (mid) [2048][EC]
  short* H2b  = (short*)U;                  // 4 MB   (late)  [8192][256]
  short* XW2T = (short*)(U + (4u << 20));   // 2 MB   (late)  [128][8192]

  const int nchunk = NE / EC;
  const int nsplit = (EC >= 16384) ? 8 : (EC == 8192 ? 4 : 2);

  hipMemsetAsync(deg, 0, (size_t)NN * 4, stream);
  hipMemsetAsync(Adj, 0, (size_t)NN * NN * 4, stream);
  hipMemsetAsync(H2all, 0, (size_t)NN * 2048 * 4, stream);

  k_deg<<<(NE + 255) / 256, 256, 0, stream>>>(dst, deg);
  k_dis<<<(NN + 255) / 256, 256, 0, stream>>>(deg, dis);
  k_adj<<<(NE + NN + 255) / 256, 256, 0, stream>>>(src, dst, dis, Adj);
  k_cast<<<NN * NN / 4 / 256, 256, 0, stream>>>((const float4*)Adj, Adjb);

  k_tr<<<FIN * FH / 256, 256, 0, stream>>>(W1, W1T, FIN, FH);
  k_tr<<<FH * FH / 256, 256, 0, stream>>>(Wm, WmT, FH, FH);
  k_tr<<<FH * FH / 256, 256, 0, stream>>>(Wm + (size_t)FH * FH, WmT + (size_t)FH * FH, FH, FH);
  k_tr<<<FH * FOUT / 256, 256, 0, stream>>>(W2, W2T, FH, FOUT);
  k_prep_min<<<dim3(NE / 64, NN / 64), 256, 0, stream>>>(m_in, m_in_bf, m_inT);
  k_cast<<<NE * NN / 4 / 256, 256, 0, stream>>>((const float4*)m_out, m_out_bf);

  // XW1T = (x @ W1)^T  bf16 [256][8192]
  gemm_mfma<0, 2, 0, false, false><<<dim3(2, 64, 1), 256, 0, stream>>>(
      nullptr, x, W1T, nullptr, XW1T, FIN, FIN, MR, FIN, 0, 1, 0, 0, 0, 0, 0, 1.0f);

  // Hb = relu(Adjb @ XW1_b + b1)  bf16 [8192][256]
  gemm_mfma<2, 0, 1, true, true><<<dim3(2, 8, NB), 256, 0, stream>>>(
      Adjb, nullptr, XW1T, b1, Hb,
      NN, 0, FH, NN, 0, 1, 1024, 0, 0, (size_t)NN * FH, 0, 1.0f);

  // G2T[(b,f)][(h,node)] = sum_c WmT[h][f][c] * Hb[b][node][c]
  gemm_mfma<2, 0, 0, false, false><<<dim3(8, 2, 16), 256, 0, stream>>>(
      WmT, nullptr, Hb, nullptr, G2T,
      FH, FH, 2048, FH, 0, 2, 0,
      (size_t)FH * FH, (size_t)NN * FH, (size_t)FH * 2048, 1024, 1.0f);

  for (int c = 0; c < nchunk; ++c) {
    // EbT = relu([m_in|m_out] @ G2T^T + bm)^T  bf16 [2048][EC]
    eg256<0, true><<<dim3(8, EC / 256, 1), 512, 0, stream>>>(
        m_in_bf + (size_t)c * EC * 1024, m_out_bf + (size_t)c * EC * 1024, 1024,
        G2T, 2048, bm, EbT, EC, 2048, 1.0f);
    // H2all += (m_inT_chunk @ Eb_chunk) / N  fp32 atomics, split-K
    eg256<1, false><<<dim3(8, 4, nsplit), 512, 0, stream>>>(
        m_inT + (size_t)c * EC, nullptr, 32768,
        EbT, EC, nullptr, H2all, 2048, EC / nsplit, 1.0f / NN);
  }

  // repack H2all -> H2b bf16 [8192][256]
  k_repack<<<MR * FH / 4 / 256, 256, 0, stream>>>(H2all, H2b);

  // XW2T = (H2b @ W2)^T  bf16 [128][8192]
  gemm_mfma<0, 0, 0, false, false><<<dim3(1, 64, 1), 256, 0, stream>>>(
      H2b, nullptr, W2T, nullptr, XW2T, FH, FH, MR, FH, 0, 1, 0, 0, 0, 0, 0, 1.0f);

  // out_b = Adjb @ XW2_b + b2  fp32 [8192][128]
  gemm_mfma<3, 0, 1, true, false><<<dim3(1, 8, NB), 256, 0, stream>>>(
      Adjb, nullptr, XW2T, b2, out,
      NN, 0, FOUT, NN, 0, 1, 1024, 0, 0, (size_t)NN * FOUT, 0, 1.0f);
}